// Round 12
// baseline (1400.800 us; speedup 1.0000x reference)
//
#include <hip/hip_runtime.h>
#include <hip/hip_bf16.h>
#include <hip/hip_fp16.h>

#define CH 64
#define RPB 128       // rows per bucket
#define RPB_SH 7
#define MAXNB 800     // max buckets supported by LDS arrays
#define CAPG 4352     // per-bucket region capacity (mean 4096 + 4 sigma)
#define BATCH 4096    // fill staging batch (LDS)
#define SPILLMAX 16384
#define GEMM_BLOCKS 1024
#define FILL_BLOCKS 391
#define ASTRIDE 65    // LDS accumulator row stride (pad 64->65 to spread banks)

typedef __attribute__((ext_vector_type(8))) _Float16 half8;
typedef __attribute__((ext_vector_type(4))) float f32x4;

// record: rec.x = (local_row << 24) | (col << 7)  [col*128 = xw row byte offset]
//         rec.y = fp32 val bits
#define COLOFF_MASK 0x00FFFF80

// ---------------------------------------------------------------------------
// Kernel 1: fused dual GEMM via MFMA, split-fp16 (x=hi+lo, W=whi+wlo) for
// fp32-grade accuracy.  Waves 0-1: xw = x@w_conv -> fp16 ws.
//                       Waves 2-3: out = x@w_lin -> fp32 d_out.
// ---------------------------------------------------------------------------
__global__ __launch_bounds__(256) void gemm_kernel(
    const float* __restrict__ x, const float* __restrict__ wc,
    const float* __restrict__ wl, __half* __restrict__ xwh,
    float* __restrict__ out, int n) {
  const int lane = threadIdx.x & 63;
  const int wv = threadIdx.x >> 6;
  const int mat = wv >> 1;   // 0: conv, 1: lin
  const int tile = wv & 1;   // row-tile within 32-row group
  const float* __restrict__ W = mat ? wl : wc;

  const int i16 = lane & 15;
  const int kseg = lane >> 4;

  half8 bhi[4][2], blo[4][2];
#pragma unroll
  for (int nt = 0; nt < 4; ++nt)
#pragma unroll
    for (int kk = 0; kk < 2; ++kk)
#pragma unroll
      for (int j = 0; j < 8; ++j) {
        const float w = W[(kk * 32 + kseg * 8 + j) * CH + nt * 16 + i16];
        const _Float16 hh = (_Float16)w;
        bhi[nt][kk][j] = hh;
        blo[nt][kk][j] = (_Float16)(w - (float)hh);
      }

  const int ngroups = (n + 31) >> 5;
  for (int g = blockIdx.x; g < ngroups; g += GEMM_BLOCKS) {
    const int base = g * 32 + tile * 16;
    const int row = base + i16;
    const int rowc = (row < n) ? row : (n - 1);
    const float* xp = x + (size_t)rowc * CH + kseg * 8;

    float af[16];
    {
      const float4 p0 = *(const float4*)(xp);
      const float4 p1 = *(const float4*)(xp + 4);
      const float4 q0 = *(const float4*)(xp + 32);
      const float4 q1 = *(const float4*)(xp + 36);
      af[0] = p0.x; af[1] = p0.y; af[2] = p0.z; af[3] = p0.w;
      af[4] = p1.x; af[5] = p1.y; af[6] = p1.z; af[7] = p1.w;
      af[8] = q0.x; af[9] = q0.y; af[10] = q0.z; af[11] = q0.w;
      af[12] = q1.x; af[13] = q1.y; af[14] = q1.z; af[15] = q1.w;
    }
    half8 ahi[2], alo[2];
#pragma unroll
    for (int kk = 0; kk < 2; ++kk)
#pragma unroll
      for (int j = 0; j < 8; ++j) {
        const float f = af[kk * 8 + j];
        const _Float16 hh = (_Float16)f;
        ahi[kk][j] = hh;
        alo[kk][j] = (_Float16)(f - (float)hh);
      }

    f32x4 acc[4];
#pragma unroll
    for (int nt = 0; nt < 4; ++nt) {
      f32x4 a = {0.f, 0.f, 0.f, 0.f};
#pragma unroll
      for (int kk = 0; kk < 2; ++kk) {
        a = __builtin_amdgcn_mfma_f32_16x16x32_f16(ahi[kk], bhi[nt][kk], a, 0, 0, 0);
        a = __builtin_amdgcn_mfma_f32_16x16x32_f16(alo[kk], bhi[nt][kk], a, 0, 0, 0);
        a = __builtin_amdgcn_mfma_f32_16x16x32_f16(ahi[kk], blo[nt][kk], a, 0, 0, 0);
      }
      acc[nt] = a;
    }

    if (mat == 0) {
#pragma unroll
      for (int nt = 0; nt < 4; ++nt)
#pragma unroll
        for (int r = 0; r < 4; ++r) {
          const int orow = base + kseg * 4 + r;
          if (orow < n)
            xwh[(size_t)orow * CH + nt * 16 + i16] = __float2half(acc[nt][r]);
        }
    } else {
#pragma unroll
      for (int nt = 0; nt < 4; ++nt)
#pragma unroll
        for (int r = 0; r < 4; ++r) {
          const int orow = base + kseg * 4 + r;
          if (orow < n)
            out[(size_t)orow * CH + nt * 16 + i16] = acc[nt][r];
        }
    }
  }
}

// ---------------------------------------------------------------------------
// Fill with runtime reservation: batches of 4096 edges staged in LDS,
// per-bucket LDS histogram, ONE global atomicAdd per (bucket,batch) reserves
// a contiguous run in the bucket's region; scatter from LDS.
// ---------------------------------------------------------------------------
__global__ __launch_bounds__(1024) void fillR_kernel(
    const int* __restrict__ r1, const int* __restrict__ c1, const float* __restrict__ v1,
    const int* __restrict__ r2, const int* __restrict__ c2, const float* __restrict__ v2,
    int* __restrict__ gcur, int* __restrict__ spillcnt, int4* __restrict__ spill,
    int2* __restrict__ ebuf, int nnz, int nb) {
  __shared__ int2 stash[BATCH];          // 32 KB
  __shared__ unsigned short sbuck[BATCH];// 8 KB
  __shared__ int hist[MAXNB];            // 3.2 KB
  __shared__ int rbase[MAXNB];           // 3.2 KB
  const int tid = threadIdx.x;
  const int tot = 2 * nnz;
  const int nbatches = (tot + BATCH - 1) / BATCH;

  for (int bt = blockIdx.x; bt < nbatches; bt += gridDim.x) {
    for (int i = tid; i < nb; i += 1024) hist[i] = 0;
    __syncthreads();

    const int e0 = bt * BATCH;
    const int m = min(BATCH, tot - e0);
    for (int i = tid; i < m; i += 1024) {
      const int e = e0 + i;
      int r, c;
      float v;
      if (e < nnz) {
        r = r1[e]; c = c1[e]; v = v1[e];
      } else {
        r = r2[e - nnz]; c = c2[e - nnz]; v = v2[e - nnz];
      }
      const int b = r >> RPB_SH;
      stash[i] = make_int2(((r & (RPB - 1)) << 24) | (c << 7), __float_as_int(v));
      sbuck[i] = (unsigned short)b;
      atomicAdd(&hist[b], 1);
    }
    __syncthreads();

    for (int b = tid; b < nb; b += 1024) {
      const int c = hist[b];
      rbase[b] = c ? atomicAdd(&gcur[b], c) : 0;
      hist[b] = 0;  // reuse as local placement cursor
    }
    __syncthreads();

    for (int i = tid; i < m; i += 1024) {
      const int b = sbuck[i];
      const int2 rec = stash[i];
      const int p = rbase[b] + atomicAdd(&hist[b], 1);
      if (p < CAPG) {
        ebuf[(size_t)b * CAPG + p] = rec;
      } else {
        const int sp = atomicAdd(spillcnt, 1);
        if (sp < SPILLMAX)
          spill[sp] = make_int4(b * RPB + (rec.x >> 24), rec.x & COLOFF_MASK,
                                rec.y, 0);
      }
    }
    __syncthreads();
  }
}

// ---------------------------------------------------------------------------
// Bucket gather, sort-free: one block per bucket. 128x64 fp32 accumulator in
// LDS (stride 65 to spread banks). Each 8-lane group consumes one UNSORTED
// record: broadcast int2 + one dwordx4 gather + 8 LDS atomicAdds. Epilogue
// fuses linear term + sigmoid.
// ---------------------------------------------------------------------------
union U8 {
  uint4 u4;
  __half h[8];
};

__global__ __launch_bounds__(512) void buckgather_kernel(
    const int* __restrict__ gcur, const int2* __restrict__ ebuf,
    const char* __restrict__ xwbytes, float4* __restrict__ outf4,
    const int* __restrict__ spillcnt, const int4* __restrict__ spill,
    int n, int nb) {
  __shared__ float acc[RPB * ASTRIDE];  // 33.3 KB
  const int tid = threadIdx.x;
  const int b = blockIdx.x;
  const int ebase = b * CAPG;
  const int cnt = min(gcur[b], CAPG);

  for (int i = tid; i < RPB * ASTRIDE; i += 512) acc[i] = 0.f;
  __syncthreads();

  const int lane = tid & 63;
  const int g = lane >> 3;        // record slot within 8
  const int l8 = lane & 7;        // channel-quad index
  const int l8b = l8 << 4;        // byte offset within xw row
  const int wv = tid >> 6;        // wave 0..7

  for (int base = wv * 16; base < cnt; base += 8 * 16) {
    const int i0 = base + g;
    const int i1 = base + 8 + g;
    const bool ok0 = i0 < cnt;
    const bool ok1 = i1 < cnt;
    const int2 rc0 = ebuf[ebase + (ok0 ? i0 : 0)];
    const int2 rc1 = ebuf[ebase + (ok1 ? i1 : 0)];
    U8 u0, u1;
    u0.u4 = *(const uint4*)(xwbytes + (rc0.x & COLOFF_MASK) + l8b);
    u1.u4 = *(const uint4*)(xwbytes + (rc1.x & COLOFF_MASK) + l8b);
    const float v0 = ok0 ? __int_as_float(rc0.y) : 0.f;
    const float v1 = ok1 ? __int_as_float(rc1.y) : 0.f;
    const int a0 = (rc0.x >> 24) * ASTRIDE + l8 * 8;
    const int a1 = (rc1.x >> 24) * ASTRIDE + l8 * 8;
#pragma unroll
    for (int k = 0; k < 8; ++k)
      atomicAdd(&acc[a0 + k], v0 * __half2float(u0.h[k]));
#pragma unroll
    for (int k = 0; k < 8; ++k)
      atomicAdd(&acc[a1 + k], v1 * __half2float(u1.h[k]));
  }

  // spill pass (empty in practice)
  const int sc = min(*spillcnt, SPILLMAX);
  for (int s = tid; s < sc; s += 512) {
    const int4 r = spill[s];
    if ((r.x >> RPB_SH) == b) {
      const int lr = r.x & (RPB - 1);
      const float v = __int_as_float(r.z);
      for (int c = 0; c < CH; c += 8) {
        U8 u;
        u.u4 = *(const uint4*)(xwbytes + r.y + c * 2);
#pragma unroll
        for (int k = 0; k < 8; ++k)
          atomicAdd(&acc[lr * ASTRIDE + c + k], v * __half2float(u.h[k]));
      }
    }
  }
  __syncthreads();

  // epilogue: out = sigmoid(linear + acc) for rows [b*RPB, b*RPB+127]
  const int row0 = b * RPB;
  for (int i = tid; i < RPB * 16; i += 512) {  // 16 float4 per row
    const int lr = i >> 4;
    const int q = i & 15;
    const int row = row0 + lr;
    if (row < n) {
      const float4 lin = outf4[(size_t)row * 16 + q];
      const float* ap = &acc[lr * ASTRIDE + q * 4];
      float4 o;
      o.x = 1.f / (1.f + __expf(-(lin.x + ap[0])));
      o.y = 1.f / (1.f + __expf(-(lin.y + ap[1])));
      o.z = 1.f / (1.f + __expf(-(lin.z + ap[2])));
      o.w = 1.f / (1.f + __expf(-(lin.w + ap[3])));
      outf4[(size_t)row * 16 + q] = o;
    }
  }
}

// ---------------------------------------------------------------------------
// Fallback path (ws too small): atomic scatter + sigmoid.
// ---------------------------------------------------------------------------
__global__ __launch_bounds__(256) void scatter_kernel(
    const int* __restrict__ rows, const int* __restrict__ cols,
    const float* __restrict__ vals, const __half* __restrict__ xwh,
    float* __restrict__ out, int nnz) {
  const int lane = threadIdx.x & 63;
  const int wid = (blockIdx.x * blockDim.x + threadIdx.x) >> 6;
  const int nwaves = (gridDim.x * blockDim.x) >> 6;
  for (int k = wid; k < nnz; k += nwaves) {
    const float xv = __half2float(xwh[(size_t)cols[k] * CH + lane]);
    atomicAdd(&out[(size_t)rows[k] * CH + lane], vals[k] * xv);
  }
}

__global__ __launch_bounds__(256) void sigmoid_kernel(float* __restrict__ out, int n4) {
  const int i = blockIdx.x * blockDim.x + threadIdx.x;
  if (i < n4) {
    float4 v = reinterpret_cast<float4*>(out)[i];
    v.x = 1.f / (1.f + __expf(-v.x));
    v.y = 1.f / (1.f + __expf(-v.y));
    v.z = 1.f / (1.f + __expf(-v.z));
    v.w = 1.f / (1.f + __expf(-v.w));
    reinterpret_cast<float4*>(out)[i] = v;
  }
}

extern "C" void kernel_launch(void* const* d_in, const int* in_sizes, int n_in,
                              void* d_out, int out_size, void* d_ws, size_t ws_size,
                              hipStream_t stream) {
  const float* x         = (const float*)d_in[0];
  const int*   down_rows = (const int*)d_in[1];
  const int*   down_cols = (const int*)d_in[2];
  const float* down_vals = (const float*)d_in[3];
  const int*   up_rows   = (const int*)d_in[4];
  const int*   up_cols   = (const int*)d_in[5];
  const float* up_vals   = (const float*)d_in[6];
  const float* w_conv    = (const float*)d_in[7];
  const float* w_lin     = (const float*)d_in[8];

  const int n   = in_sizes[0] / CH;  // 100000
  const int nnz = in_sizes[1];       // 1600000
  const int nb  = (n + RPB - 1) / RPB;  // 782

  float* out = (float*)d_out;

  // ws layout (xw stored as fp16)
  char* p = (char*)d_ws;
  __half* xwh  = (__half*)p;  p += (size_t)n * CH * 2;
  int* gcur    = (int*)p;  p += (size_t)nb * 4;
  int* spillc  = (int*)p;  p += 16;           // spill counter (+pad)
  p = (char*)(((uintptr_t)p + 15) & ~(uintptr_t)15);
  int4* spill  = (int4*)p; p += (size_t)SPILLMAX * 16;
  int2* ebuf   = (int2*)p; p += (size_t)nb * CAPG * 8;
  const size_t need = (size_t)(p - (char*)d_ws);

  if (ws_size >= need && nb <= MAXNB && n < (1 << 17)) {
    hipMemsetAsync(gcur, 0, (size_t)nb * 4 + 16, stream);  // gcur + spillc
    gemm_kernel<<<GEMM_BLOCKS, 256, 0, stream>>>(x, w_conv, w_lin, xwh, out, n);
    fillR_kernel<<<FILL_BLOCKS, 1024, 0, stream>>>(
        down_rows, down_cols, down_vals, up_rows, up_cols, up_vals,
        gcur, spillc, spill, ebuf, nnz, nb);
    buckgather_kernel<<<nb, 512, 0, stream>>>(gcur, ebuf, (const char*)xwh,
                                              (float4*)out, spillc, spill, n, nb);
  } else {
    gemm_kernel<<<GEMM_BLOCKS, 256, 0, stream>>>(x, w_conv, w_lin, xwh, out, n);
    scatter_kernel<<<4096, 256, 0, stream>>>(down_rows, down_cols, down_vals, xwh, out, nnz);
    scatter_kernel<<<4096, 256, 0, stream>>>(up_rows, up_cols, up_vals, xwh, out, nnz);
    const int n4 = (n * CH) / 4;
    sigmoid_kernel<<<(n4 + 255) / 256, 256, 0, stream>>>(out, n4);
  }
}

// Round 13
// 141.233 us; speedup vs baseline: 9.9183x; 9.9183x over previous
//
#include <hip/hip_runtime.h>
#include <hip/hip_bf16.h>
#include <hip/hip_fp16.h>

#define CH 64
#define RPB 128       // rows per bucket
#define RPB_SH 7
#define MAXNB 800     // max buckets supported by LDS arrays
#define CAPG 4352     // per-bucket region capacity (mean 4096 + 4 sigma)
#define BATCH 4096    // fill staging batch (LDS)
#define SPILLMAX 16384
#define FILL_BLOCKS 391
#define GEMM_PHYS 512           // physical gemm blocks (512 thr, 2 virtual each)
#define NVB (GEMM_PHYS * 2)     // virtual 256-thread gemm blocks

typedef __attribute__((ext_vector_type(8))) _Float16 half8;
typedef __attribute__((ext_vector_type(4))) float f32x4;

// record: rec.x = (local_row << 24) | (col << 7)  [col*128 = xw row byte offset]
//         rec.y = fp32 val bits
#define COLOFF_MASK 0x00FFFF80

// ---------------------------------------------------------------------------
// Merged kernel: blocks [0, FILL_BLOCKS) run the reservation-fill;
// blocks [FILL_BLOCKS, FILL_BLOCKS+GEMM_PHYS) run the dual GEMM as two
// virtual 256-thread blocks. Independent work -> fill hides under gemm.
// ---------------------------------------------------------------------------
__global__ __launch_bounds__(512) void gemm_fill_kernel(
    const float* __restrict__ x, const float* __restrict__ wc,
    const float* __restrict__ wl, __half* __restrict__ xwh,
    float* __restrict__ out, int n,
    const int* __restrict__ r1, const int* __restrict__ c1, const float* __restrict__ v1,
    const int* __restrict__ r2, const int* __restrict__ c2, const float* __restrict__ v2,
    int* __restrict__ gcur, int* __restrict__ spillcnt, int4* __restrict__ spill,
    int2* __restrict__ ebuf, int nnz, int nb) {
  __shared__ int2 stash[BATCH];           // 32 KB
  __shared__ unsigned short sbuck[BATCH]; // 8 KB
  __shared__ int hist[MAXNB];             // 3.2 KB
  __shared__ int rbase[MAXNB];            // 3.2 KB

  const int tid = threadIdx.x;

  if (blockIdx.x < (unsigned)FILL_BLOCKS) {
    // ---- fill path (R10/R11 winner, 512 threads) ----
    const int tot = 2 * nnz;
    const int nbatches = (tot + BATCH - 1) / BATCH;
    for (int bt = blockIdx.x; bt < nbatches; bt += FILL_BLOCKS) {
      for (int i = tid; i < nb; i += 512) hist[i] = 0;
      __syncthreads();

      const int e0 = bt * BATCH;
      const int m = min(BATCH, tot - e0);
      for (int i = tid; i < m; i += 512) {
        const int e = e0 + i;
        int r, c;
        float v;
        if (e < nnz) {
          r = r1[e]; c = c1[e]; v = v1[e];
        } else {
          r = r2[e - nnz]; c = c2[e - nnz]; v = v2[e - nnz];
        }
        const int b = r >> RPB_SH;
        stash[i] = make_int2(((r & (RPB - 1)) << 24) | (c << 7), __float_as_int(v));
        sbuck[i] = (unsigned short)b;
        atomicAdd(&hist[b], 1);
      }
      __syncthreads();

      for (int b = tid; b < nb; b += 512) {
        const int c = hist[b];
        rbase[b] = c ? atomicAdd(&gcur[b], c) : 0;
        hist[b] = 0;  // reuse as local placement cursor
      }
      __syncthreads();

      for (int i = tid; i < m; i += 512) {
        const int b = sbuck[i];
        const int2 rec = stash[i];
        const int p = rbase[b] + atomicAdd(&hist[b], 1);
        if (p < CAPG) {
          ebuf[(size_t)b * CAPG + p] = rec;
        } else {
          const int sp = atomicAdd(spillcnt, 1);
          if (sp < SPILLMAX)
            spill[sp] = make_int4(b * RPB + (rec.x >> 24), rec.x & COLOFF_MASK,
                                  rec.y, 0);
        }
      }
      __syncthreads();
    }
    return;
  }

  // ---- GEMM path: virtual 256-thread block ----
  const int vb = (int)(blockIdx.x - FILL_BLOCKS) * 2 + (tid >> 8);
  const int t256 = tid & 255;
  const int lane = t256 & 63;
  const int wv = t256 >> 6;
  const int mat = wv >> 1;   // 0: conv, 1: lin
  const int tile = wv & 1;   // row-tile within 32-row group
  const float* __restrict__ W = mat ? wl : wc;

  const int i16 = lane & 15;
  const int kseg = lane >> 4;

  half8 bhi[4][2], blo[4][2];
#pragma unroll
  for (int nt = 0; nt < 4; ++nt)
#pragma unroll
    for (int kk = 0; kk < 2; ++kk)
#pragma unroll
      for (int j = 0; j < 8; ++j) {
        const float w = W[(kk * 32 + kseg * 8 + j) * CH + nt * 16 + i16];
        const _Float16 hh = (_Float16)w;
        bhi[nt][kk][j] = hh;
        blo[nt][kk][j] = (_Float16)(w - (float)hh);
      }

  const int ngroups = (n + 31) >> 5;
  for (int g = vb; g < ngroups; g += NVB) {
    const int base = g * 32 + tile * 16;
    const int row = base + i16;
    const int rowc = (row < n) ? row : (n - 1);
    const float* xp = x + (size_t)rowc * CH + kseg * 8;

    float af[16];
    {
      const float4 p0 = *(const float4*)(xp);
      const float4 p1 = *(const float4*)(xp + 4);
      const float4 q0 = *(const float4*)(xp + 32);
      const float4 q1 = *(const float4*)(xp + 36);
      af[0] = p0.x; af[1] = p0.y; af[2] = p0.z; af[3] = p0.w;
      af[4] = p1.x; af[5] = p1.y; af[6] = p1.z; af[7] = p1.w;
      af[8] = q0.x; af[9] = q0.y; af[10] = q0.z; af[11] = q0.w;
      af[12] = q1.x; af[13] = q1.y; af[14] = q1.z; af[15] = q1.w;
    }
    half8 ahi[2], alo[2];
#pragma unroll
    for (int kk = 0; kk < 2; ++kk)
#pragma unroll
      for (int j = 0; j < 8; ++j) {
        const float f = af[kk * 8 + j];
        const _Float16 hh = (_Float16)f;
        ahi[kk][j] = hh;
        alo[kk][j] = (_Float16)(f - (float)hh);
      }

    f32x4 acc[4];
#pragma unroll
    for (int nt = 0; nt < 4; ++nt) {
      f32x4 a = {0.f, 0.f, 0.f, 0.f};
#pragma unroll
      for (int kk = 0; kk < 2; ++kk) {
        a = __builtin_amdgcn_mfma_f32_16x16x32_f16(ahi[kk], bhi[nt][kk], a, 0, 0, 0);
        a = __builtin_amdgcn_mfma_f32_16x16x32_f16(alo[kk], bhi[nt][kk], a, 0, 0, 0);
        a = __builtin_amdgcn_mfma_f32_16x16x32_f16(ahi[kk], blo[nt][kk], a, 0, 0, 0);
      }
      acc[nt] = a;
    }

    if (mat == 0) {
#pragma unroll
      for (int nt = 0; nt < 4; ++nt)
#pragma unroll
        for (int r = 0; r < 4; ++r) {
          const int orow = base + kseg * 4 + r;
          if (orow < n)
            xwh[(size_t)orow * CH + nt * 16 + i16] = __float2half(acc[nt][r]);
        }
    } else {
#pragma unroll
      for (int nt = 0; nt < 4; ++nt)
#pragma unroll
        for (int r = 0; r < 4; ++r) {
          const int orow = base + kseg * 4 + r;
          if (orow < n)
            out[(size_t)orow * CH + nt * 16 + i16] = acc[nt][r];
        }
    }
  }
}

// ---------------------------------------------------------------------------
// In-bucket counting sort (one block per bucket). 512 thr, ~36 KB LDS.
// Emits packed rowinfo[gr] = (row_start_offset << 16) | row_count.
// ---------------------------------------------------------------------------
__global__ __launch_bounds__(512) void sortB_kernel(
    const int* __restrict__ gcur, int2* __restrict__ ebuf,
    unsigned int* __restrict__ rowinfo, int n, int nb) {
  __shared__ int2 raw[CAPG];  // 34.8 KB
  __shared__ int hist[RPB];
  __shared__ int sc[RPB];
  __shared__ int cur[RPB];
  const int b = blockIdx.x;
  const int beg = b * CAPG;
  const int cnt = min(gcur[b], CAPG);

  if (threadIdx.x < RPB) hist[threadIdx.x] = 0;
  __syncthreads();

  for (int i = threadIdx.x; i < cnt; i += 512) {
    const int2 rec = ebuf[beg + i];
    raw[i] = rec;
    atomicAdd(&hist[rec.x >> 24], 1);
  }
  __syncthreads();

  int v = 0;
  if (threadIdx.x < RPB) {
    v = hist[threadIdx.x];
    sc[threadIdx.x] = v;
  }
  __syncthreads();
  for (int off = 1; off < RPB; off <<= 1) {
    int t = 0;
    if (threadIdx.x < RPB && threadIdx.x >= off) t = sc[threadIdx.x - off];
    __syncthreads();
    if (threadIdx.x < RPB) sc[threadIdx.x] += t;
    __syncthreads();
  }
  if (threadIdx.x < RPB) {
    const int ex = sc[threadIdx.x] - v;  // exclusive start
    cur[threadIdx.x] = ex;
    const int gr = b * RPB + threadIdx.x;
    if (gr < n) rowinfo[gr] = ((unsigned int)ex << 16) | (unsigned int)v;
  }
  __syncthreads();

  for (int i = threadIdx.x; i < cnt; i += 512) {
    const int2 rec = raw[i];
    const int pos = atomicAdd(&cur[rec.x >> 24], 1);
    ebuf[beg + pos] = rec;
  }
}

// ---------------------------------------------------------------------------
// Row gather — 8-lane-group dwordx4 scheme; fp16 xw via v_fma_mix.
// ---------------------------------------------------------------------------
union U8 {
  uint4 u4;
  __half h[8];
};

__device__ __forceinline__ void edge_fma(float* a, const U8& u, float v) {
#pragma unroll
  for (int k = 0; k < 8; ++k)
    a[k] = fmaf(v, __half2float(u.h[k]), a[k]);
}

__global__ __launch_bounds__(256) void gather_kernel(
    const unsigned int* __restrict__ rowinfo, const int2* __restrict__ ebuf,
    const char* __restrict__ xwbytes, float4* __restrict__ outf4,
    const int* __restrict__ spillcnt, const int4* __restrict__ spill,
    int n) {
  const int lane = threadIdx.x & 63;
  const int g = lane >> 3;        // edge slot 0..7
  const int l8 = lane & 7;        // channel-quad index
  const int l8b = l8 << 4;        // byte offset within row
  const int w = (blockIdx.x * blockDim.x + threadIdx.x) >> 6;
  const int nw = (gridDim.x * blockDim.x) >> 6;
  const int sc = min(*spillcnt, SPILLMAX);

  for (int row = w; row < n; row += nw) {
    const float4 lin0 = outf4[(size_t)row * 16 + 2 * l8];
    const float4 lin1 = outf4[(size_t)row * 16 + 2 * l8 + 1];

    float a[8];
#pragma unroll
    for (int k = 0; k < 8; ++k) a[k] = 0.f;

    const unsigned int info = rowinfo[row];
    const int beg = (row >> RPB_SH) * CAPG + (int)(info >> 16);
    const int end = beg + (int)(info & 0xFFFFu);

    int e = beg;
    for (; e + 16 <= end; e += 16) {
      const int2 rc0 = ebuf[e + g];
      const int2 rc1 = ebuf[e + 8 + g];
      U8 u0, u1;
      u0.u4 = *(const uint4*)(xwbytes + (rc0.x & COLOFF_MASK) + l8b);
      u1.u4 = *(const uint4*)(xwbytes + (rc1.x & COLOFF_MASK) + l8b);
      edge_fma(a, u0, __int_as_float(rc0.y));
      edge_fma(a, u1, __int_as_float(rc1.y));
    }
    for (; e < end; e += 8) {
      const int idx = e + g;
      const bool ok = idx < end;
      const int2 rc = ebuf[ok ? idx : (end - 1)];
      U8 u;
      u.u4 = *(const uint4*)(xwbytes + (rc.x & COLOFF_MASK) + l8b);
      edge_fma(a, u, ok ? __int_as_float(rc.y) : 0.f);
    }

    if (sc > 0) {  // spill pass (empty in practice; uniform branch)
      for (int s = 0; s < sc; ++s) {
        const int4 r = spill[s];
        if (r.x == row && g == 0) {
          U8 u;
          u.u4 = *(const uint4*)(xwbytes + r.y + l8b);
          edge_fma(a, u, __int_as_float(r.z));
        }
      }
    }

    // butterfly merge across the 8 groups
#pragma unroll
    for (int k = 0; k < 8; ++k) {
      a[k] += __shfl_xor(a[k], 8, 64);
      a[k] += __shfl_xor(a[k], 16, 64);
      a[k] += __shfl_xor(a[k], 32, 64);
    }

    if (lane < 8) {  // g == 0: l8 = lane
      float4 o0, o1;
      o0.x = 1.f / (1.f + __expf(-(lin0.x + a[0])));
      o0.y = 1.f / (1.f + __expf(-(lin0.y + a[1])));
      o0.z = 1.f / (1.f + __expf(-(lin0.z + a[2])));
      o0.w = 1.f / (1.f + __expf(-(lin0.w + a[3])));
      o1.x = 1.f / (1.f + __expf(-(lin1.x + a[4])));
      o1.y = 1.f / (1.f + __expf(-(lin1.y + a[5])));
      o1.z = 1.f / (1.f + __expf(-(lin1.z + a[6])));
      o1.w = 1.f / (1.f + __expf(-(lin1.w + a[7])));
      outf4[(size_t)row * 16 + 2 * l8] = o0;
      outf4[(size_t)row * 16 + 2 * l8 + 1] = o1;
    }
  }
}

// ---------------------------------------------------------------------------
// Fallback path (ws too small): gemm-only + atomic scatter + sigmoid.
// ---------------------------------------------------------------------------
__global__ __launch_bounds__(256) void gemm_kernel(
    const float* __restrict__ x, const float* __restrict__ wc,
    const float* __restrict__ wl, __half* __restrict__ xwh,
    float* __restrict__ out, int n) {
  const int lane = threadIdx.x & 63;
  const int wv = threadIdx.x >> 6;
  const int mat = wv >> 1;
  const int tile = wv & 1;
  const float* __restrict__ W = mat ? wl : wc;
  const int i16 = lane & 15;
  const int kseg = lane >> 4;

  half8 bhi[4][2], blo[4][2];
#pragma unroll
  for (int nt = 0; nt < 4; ++nt)
#pragma unroll
    for (int kk = 0; kk < 2; ++kk)
#pragma unroll
      for (int j = 0; j < 8; ++j) {
        const float w = W[(kk * 32 + kseg * 8 + j) * CH + nt * 16 + i16];
        const _Float16 hh = (_Float16)w;
        bhi[nt][kk][j] = hh;
        blo[nt][kk][j] = (_Float16)(w - (float)hh);
      }

  const int ngroups = (n + 31) >> 5;
  for (int g = blockIdx.x; g < ngroups; g += gridDim.x) {
    const int base = g * 32 + tile * 16;
    const int row = base + i16;
    const int rowc = (row < n) ? row : (n - 1);
    const float* xp = x + (size_t)rowc * CH + kseg * 8;
    float af[16];
    {
      const float4 p0 = *(const float4*)(xp);
      const float4 p1 = *(const float4*)(xp + 4);
      const float4 q0 = *(const float4*)(xp + 32);
      const float4 q1 = *(const float4*)(xp + 36);
      af[0] = p0.x; af[1] = p0.y; af[2] = p0.z; af[3] = p0.w;
      af[4] = p1.x; af[5] = p1.y; af[6] = p1.z; af[7] = p1.w;
      af[8] = q0.x; af[9] = q0.y; af[10] = q0.z; af[11] = q0.w;
      af[12] = q1.x; af[13] = q1.y; af[14] = q1.z; af[15] = q1.w;
    }
    half8 ahi[2], alo[2];
#pragma unroll
    for (int kk = 0; kk < 2; ++kk)
#pragma unroll
      for (int j = 0; j < 8; ++j) {
        const float f = af[kk * 8 + j];
        const _Float16 hh = (_Float16)f;
        ahi[kk][j] = hh;
        alo[kk][j] = (_Float16)(f - (float)hh);
      }
    f32x4 acc[4];
#pragma unroll
    for (int nt = 0; nt < 4; ++nt) {
      f32x4 a = {0.f, 0.f, 0.f, 0.f};
#pragma unroll
      for (int kk = 0; kk < 2; ++kk) {
        a = __builtin_amdgcn_mfma_f32_16x16x32_f16(ahi[kk], bhi[nt][kk], a, 0, 0, 0);
        a = __builtin_amdgcn_mfma_f32_16x16x32_f16(alo[kk], bhi[nt][kk], a, 0, 0, 0);
        a = __builtin_amdgcn_mfma_f32_16x16x32_f16(ahi[kk], blo[nt][kk], a, 0, 0, 0);
      }
      acc[nt] = a;
    }
    if (mat == 0) {
#pragma unroll
      for (int nt = 0; nt < 4; ++nt)
#pragma unroll
        for (int r = 0; r < 4; ++r) {
          const int orow = base + kseg * 4 + r;
          if (orow < n)
            xwh[(size_t)orow * CH + nt * 16 + i16] = __float2half(acc[nt][r]);
        }
    } else {
#pragma unroll
      for (int nt = 0; nt < 4; ++nt)
#pragma unroll
        for (int r = 0; r < 4; ++r) {
          const int orow = base + kseg * 4 + r;
          if (orow < n)
            out[(size_t)orow * CH + nt * 16 + i16] = acc[nt][r];
        }
    }
  }
}

__global__ __launch_bounds__(256) void scatter_kernel(
    const int* __restrict__ rows, const int* __restrict__ cols,
    const float* __restrict__ vals, const __half* __restrict__ xwh,
    float* __restrict__ out, int nnz) {
  const int lane = threadIdx.x & 63;
  const int wid = (blockIdx.x * blockDim.x + threadIdx.x) >> 6;
  const int nwaves = (gridDim.x * blockDim.x) >> 6;
  for (int k = wid; k < nnz; k += nwaves) {
    const float xv = __half2float(xwh[(size_t)cols[k] * CH + lane]);
    atomicAdd(&out[(size_t)rows[k] * CH + lane], vals[k] * xv);
  }
}

__global__ __launch_bounds__(256) void sigmoid_kernel(float* __restrict__ out, int n4) {
  const int i = blockIdx.x * blockDim.x + threadIdx.x;
  if (i < n4) {
    float4 v = reinterpret_cast<float4*>(out)[i];
    v.x = 1.f / (1.f + __expf(-v.x));
    v.y = 1.f / (1.f + __expf(-v.y));
    v.z = 1.f / (1.f + __expf(-v.z));
    v.w = 1.f / (1.f + __expf(-v.w));
    reinterpret_cast<float4*>(out)[i] = v;
  }
}

extern "C" void kernel_launch(void* const* d_in, const int* in_sizes, int n_in,
                              void* d_out, int out_size, void* d_ws, size_t ws_size,
                              hipStream_t stream) {
  const float* x         = (const float*)d_in[0];
  const int*   down_rows = (const int*)d_in[1];
  const int*   down_cols = (const int*)d_in[2];
  const float* down_vals = (const float*)d_in[3];
  const int*   up_rows   = (const int*)d_in[4];
  const int*   up_cols   = (const int*)d_in[5];
  const float* up_vals   = (const float*)d_in[6];
  const float* w_conv    = (const float*)d_in[7];
  const float* w_lin     = (const float*)d_in[8];

  const int n   = in_sizes[0] / CH;  // 100000
  const int nnz = in_sizes[1];       // 1600000
  const int nb  = (n + RPB - 1) / RPB;  // 782

  float* out = (float*)d_out;

  // ws layout (xw stored as fp16)
  char* p = (char*)d_ws;
  __half* xwh  = (__half*)p;  p += (size_t)n * CH * 2;
  int* gcur    = (int*)p;  p += (size_t)nb * 4;
  int* spillc  = (int*)p;  p += 16;           // spill counter (+pad)
  unsigned int* rowinfo = (unsigned int*)p;  p += ((size_t)n + 2) * 4;
  p = (char*)(((uintptr_t)p + 15) & ~(uintptr_t)15);
  int4* spill  = (int4*)p; p += (size_t)SPILLMAX * 16;
  int2* ebuf   = (int2*)p; p += (size_t)nb * CAPG * 8;
  const size_t need = (size_t)(p - (char*)d_ws);

  if (ws_size >= need && nb <= MAXNB && n < (1 << 17)) {
    hipMemsetAsync(gcur, 0, (size_t)nb * 4 + 16, stream);  // gcur + spillc
    gemm_fill_kernel<<<FILL_BLOCKS + GEMM_PHYS, 512, 0, stream>>>(
        x, w_conv, w_lin, xwh, out, n,
        down_rows, down_cols, down_vals, up_rows, up_cols, up_vals,
        gcur, spillc, spill, ebuf, nnz, nb);
    sortB_kernel<<<nb, 512, 0, stream>>>(gcur, ebuf, rowinfo, n, nb);
    const int nblk = (n + 3) / 4;
    gather_kernel<<<nblk, 256, 0, stream>>>(rowinfo, ebuf, (const char*)xwh,
                                            (float4*)out, spillc, spill, n);
  } else {
    gemm_kernel<<<1024, 256, 0, stream>>>(x, w_conv, w_lin, xwh, out, n);
    scatter_kernel<<<4096, 256, 0, stream>>>(down_rows, down_cols, down_vals, xwh, out, nnz);
    scatter_kernel<<<4096, 256, 0, stream>>>(up_rows, up_cols, up_vals, xwh, out, nnz);
    const int n4 = (n * CH) / 4;
    sigmoid_kernel<<<(n4 + 255) / 256, 256, 0, stream>>>(out, n4);
  }
}